// Round 2
// baseline (1290.291 us; speedup 1.0000x reference)
//
#include <hip/hip_runtime.h>
#include <float.h>
#include <math.h>

// ---------------------------------------------------------------------------
// Stage 1: SPP — spatial pyramid max pool, levels (4,3,2,1) over 192x192.
// One block per (frame, channel). 192 threads = one per column.
// 192 rows = 12 chunks of 16; every level bin boundary is a chunk boundary.
// ---------------------------------------------------------------------------
__global__ __launch_bounds__(192) void spp_kernel(const float* __restrict__ frames,
                                                  float* __restrict__ pooled) {
    int bc = blockIdx.x;            // s*3 + c
    int w  = threadIdx.x;           // column 0..191
    const float* img = frames + (size_t)bc * (192 * 192);

    float cm[12];
#pragma unroll
    for (int ch = 0; ch < 12; ++ch) {
        float m = -FLT_MAX;
#pragma unroll
        for (int r = 0; r < 16; ++r)
            m = fmaxf(m, img[(ch * 16 + r) * 192 + w]);
        cm[ch] = m;
    }

    __shared__ float band[10][192];
#pragma unroll
    for (int i = 0; i < 4; ++i)     // level-4 row bands: 3 chunks each
        band[i][w] = fmaxf(fmaxf(cm[3*i], cm[3*i+1]), cm[3*i+2]);
#pragma unroll
    for (int i = 0; i < 3; ++i)     // level-3 row bands: 4 chunks each
        band[4+i][w] = fmaxf(fmaxf(cm[4*i], cm[4*i+1]), fmaxf(cm[4*i+2], cm[4*i+3]));
#pragma unroll
    for (int i = 0; i < 2; ++i) {   // level-2 row bands: 6 chunks each
        float m = cm[6*i];
#pragma unroll
        for (int k = 1; k < 6; ++k) m = fmaxf(m, cm[6*i+k]);
        band[7+i][w] = m;
    }
    {
        float m = cm[0];
#pragma unroll
        for (int k = 1; k < 12; ++k) m = fmaxf(m, cm[k]);
        band[9][w] = m;
    }
    __syncthreads();

    int s = bc / 3, c = bc % 3;
    float* orow = pooled + s * 90;
    int t = w;
    if (t < 16) {                    // level 4: out idx c*16 + r*4 + cc
        int r = t >> 2, cc = t & 3;
        float m = -FLT_MAX;
        for (int x = cc * 48; x < cc * 48 + 48; ++x) m = fmaxf(m, band[r][x]);
        orow[c * 16 + t] = m;
    } else if (t < 25) {             // level 3: 48 + c*9 + idx
        int idx = t - 16, r = idx / 3, cc = idx % 3;
        float m = -FLT_MAX;
        for (int x = cc * 64; x < cc * 64 + 64; ++x) m = fmaxf(m, band[4 + r][x]);
        orow[48 + c * 9 + idx] = m;
    } else if (t < 29) {             // level 2: 75 + c*4 + idx
        int idx = t - 25, r = idx >> 1, cc = idx & 1;
        float m = -FLT_MAX;
        for (int x = cc * 96; x < cc * 96 + 96; ++x) m = fmaxf(m, band[7 + r][x]);
        orow[75 + c * 4 + idx] = m;
    } else if (t == 29) {            // level 1: 87 + c
        float m = -FLT_MAX;
        for (int x = 0; x < 192; ++x) m = fmaxf(m, band[9][x]);
        orow[87 + c] = m;
    }
}

// ---------------------------------------------------------------------------
// Stage 2: pooled(512,90) @ W_spp(4096,90)^T + b -> relu -> prelu(512,4096)
// ---------------------------------------------------------------------------
__global__ __launch_bounds__(256) void fc_spp_kernel(const float* __restrict__ pooled,
                                                     const float* __restrict__ W,
                                                     const float* __restrict__ b,
                                                     float* __restrict__ out) {
    int ec = blockIdx.x;            // 0..3   (1024 outputs each)
    int fc = blockIdx.y;            // 0..63  (8 frames each)
    int t  = threadIdx.x;
    int s0 = fc * 8;

    __shared__ __align__(16) float sp[90 * 8];   // sp[j*8 + f]
    for (int i = t; i < 720; i += 256) {
        int j = i >> 3, f = i & 7;
        sp[i] = pooled[(s0 + f) * 90 + j];
    }
    __syncthreads();

    int e0 = ec * 1024 + t;
    float acc[4][8];
#pragma unroll
    for (int k = 0; k < 4; ++k) {
        float bb = b[e0 + k * 256];
#pragma unroll
        for (int f = 0; f < 8; ++f) acc[k][f] = bb;
    }
    for (int j = 0; j < 90; ++j) {
        float w0 = W[(e0 + 0 * 256) * 90 + j];
        float w1 = W[(e0 + 1 * 256) * 90 + j];
        float w2 = W[(e0 + 2 * 256) * 90 + j];
        float w3 = W[(e0 + 3 * 256) * 90 + j];
        float4 pa = *(const float4*)&sp[j * 8 + 0];
        float4 pb = *(const float4*)&sp[j * 8 + 4];
        float pv[8] = {pa.x, pa.y, pa.z, pa.w, pb.x, pb.y, pb.z, pb.w};
#pragma unroll
        for (int f = 0; f < 8; ++f) {
            acc[0][f] += w0 * pv[f];
            acc[1][f] += w1 * pv[f];
            acc[2][f] += w2 * pv[f];
            acc[3][f] += w3 * pv[f];
        }
    }
#pragma unroll
    for (int k = 0; k < 4; ++k)
#pragma unroll
        for (int f = 0; f < 8; ++f)
            out[(size_t)(s0 + f) * 4096 + e0 + k * 256] = fmaxf(acc[k][f], 0.f);
}

// ---------------------------------------------------------------------------
// Stage 3: prelu(512,4096) @ {W_fc7,W_fcast}(64,4096)^T -> relu
// ---------------------------------------------------------------------------
__global__ __launch_bounds__(512) void fc7cast_kernel(const float* __restrict__ prelu,
                                                      const float* __restrict__ W7,
                                                      const float* __restrict__ b7,
                                                      const float* __restrict__ Wc,
                                                      const float* __restrict__ bc,
                                                      float* __restrict__ emb,
                                                      float* __restrict__ fca) {
    int blk = blockIdx.x;           // 0..127
    int t   = threadIdx.x;          // 0..511
    int s0  = blk * 4;

    __shared__ __align__(16) float pr[4 * 4096];   // 64 KB
    const float4* src = (const float4*)(prelu + (size_t)s0 * 4096);
    float4* dst = (float4*)pr;
    for (int i = t; i < 4096; i += 512) dst[i] = src[i];
    __syncthreads();

    int o = t & 127;                // output 0..127 (64 emb + 64 fcast)
    int f = t >> 7;                 // frame 0..3 (wave-uniform)
    const float* wr;
    float bias;
    if (o < 64) { wr = W7 + (size_t)o * 4096; bias = b7[o]; }
    else        { wr = Wc + (size_t)(o - 64) * 4096; bias = bc[o - 64]; }

    const float4* w4 = (const float4*)wr;
    const float4* p4 = (const float4*)(pr + f * 4096);
    float a0 = 0.f, a1 = 0.f, a2 = 0.f, a3 = 0.f;
    for (int j = 0; j < 1024; ++j) {
        float4 wv = w4[j];
        float4 pv = p4[j];
        a0 += wv.x * pv.x; a1 += wv.y * pv.y;
        a2 += wv.z * pv.z; a3 += wv.w * pv.w;
    }
    float a = fmaxf(a0 + a1 + a2 + a3 + bias, 0.f);
    if (o < 64) emb[(s0 + f) * 64 + o] = a;
    else        fca[(s0 + f) * 64 + (o - 64)] = a;
}

// ---------------------------------------------------------------------------
// Stage 4: precompute input-gate contributions for cell1 (main + forecast):
// gm[s][g] = Wih1[g,:]·emb[s] + bih1[g] + bhh1[g];  gf likewise with fcast.
// ---------------------------------------------------------------------------
__global__ __launch_bounds__(256) void pregate_kernel(const float* __restrict__ emb,
                                                      const float* __restrict__ fca,
                                                      const float* __restrict__ Wih1,
                                                      const float* __restrict__ bih1,
                                                      const float* __restrict__ bhh1,
                                                      float* __restrict__ gm,
                                                      float* __restrict__ gf) {
    int s = blockIdx.x;
    int t = threadIdx.x;            // gate 0..255
    __shared__ float x[64], fx[64];
    if (t < 64) x[t] = emb[s * 64 + t];
    else if (t < 128) fx[t - 64] = fca[s * 64 + (t - 64)];
    __syncthreads();

    const float* wr = Wih1 + t * 64;
    float am = bih1[t] + bhh1[t];
    float af = am;
#pragma unroll
    for (int j = 0; j < 64; ++j) {
        float w = wr[j];
        am += w * x[j];
        af += w * fx[j];
    }
    gm[s * 256 + t] = am;
    gf[s * 256 + t] = af;
}

// ---------------------------------------------------------------------------
// Stage 5: MAIN sequential scan only (forecast is recurrence-free and moved
// to a parallel kernel). ONE block, 256 threads. Per step:
//   A: cell1 gates (256 x 64-MAC, 4-way acc split)        [bar]
//   B: finish h1/c1 (c1 in private regs), store trajectory [bar]
//   C: cell2 gates SPLIT: t<128 Wih2·h1 (64-MAC) || t>=128 Whh2·h2 (32-MAC)
//                                                          [bar]
//   D: sum partials, activations, finish h2/c2, store trajectory
//   (no end-of-loop barrier needed: D's writes race with nothing A touches)
// ---------------------------------------------------------------------------
__device__ __forceinline__ float sigf(float x) { return 1.f / (1.f + expf(-x)); }
__device__ __forceinline__ float act_fun(float x, int type) {
    return (type == 2) ? tanhf(x) : sigf(x);
}

__global__ __launch_bounds__(256) void lstm_main_kernel(const float* __restrict__ gm,
                                                        const float* __restrict__ Whh1,
                                                        const float* __restrict__ Wih2,
                                                        const float* __restrict__ Whh2,
                                                        const float* __restrict__ bih2,
                                                        const float* __restrict__ bhh2,
                                                        float* __restrict__ h1t,
                                                        float* __restrict__ c1t,
                                                        float* __restrict__ h2t,
                                                        float* __restrict__ c2t) {
    int t = threadIdx.x;

    __shared__ __align__(16) float h1s[64];
    __shared__ __align__(16) float h2s[32];
    __shared__ float act1[256];
    __shared__ float act2[128];     // Wih2·h1 + b2 partial
    __shared__ float act2p[128];    // Whh2·h2 partial

    // Whh1 row for gate t (all 256 threads)
    float wh[64];
#pragma unroll
    for (int j = 0; j < 64; ++j) wh[j] = Whh1[t * 64 + j];

    // cell2 rows: t<128 -> Wih2 row t (64); t>=128 -> Whh2 row t-128 (32)
    float wu[64];
#pragma unroll
    for (int j = 0; j < 64; ++j) wu[j] = 0.f;
    float b2 = 0.f;
    if (t < 128) {
#pragma unroll
        for (int j = 0; j < 64; ++j) wu[j] = Wih2[t * 64 + j];
        b2 = bih2[t] + bhh2[t];
    } else {
#pragma unroll
        for (int j = 0; j < 32; ++j) wu[j] = Whh2[(t - 128) * 32 + j];
    }

    float c1r = 0.f;                // private c1 (valid for t<64)
    float c2r = 0.f;                // private c2 (valid for t<32)
    if (t < 64) h1s[t] = 0.f;
    if (t < 32) h2s[t] = 0.f;
    __syncthreads();

    float gmv = gm[t];              // prefetched input-gate term for step 0

    for (int s = 0; s < 512; ++s) {
        // prefetch next step's gm while this step computes
        float gnext = (s < 511) ? gm[(s + 1) * 256 + t] : 0.f;

        // ---- A: cell1 recurrent gates (reads old h1), 4-way acc split
        {
            float a0 = 0.f, a1 = 0.f, a2 = 0.f, a3 = 0.f;
#pragma unroll
            for (int j = 0; j < 16; ++j) {
                float4 h = ((const float4*)h1s)[j];
                a0 += wh[4*j+0] * h.x; a1 += wh[4*j+1] * h.y;
                a2 += wh[4*j+2] * h.z; a3 += wh[4*j+3] * h.w;
            }
            act1[t] = act_fun(gmv + ((a0 + a1) + (a2 + a3)), t >> 6);
        }
        gmv = gnext;
        __syncthreads();

        // ---- B: finish cell1 (h1, private c1), store trajectory
        if (t < 64) {
            float iv = act1[t], fv = act1[64+t], gv = act1[128+t], ov = act1[192+t];
            float cn = fv * c1r + iv * gv;
            c1r = cn;
            float hn = ov * tanhf(cn);
            h1s[t] = hn;
            h1t[s * 64 + t] = hn;
            c1t[s * 64 + t] = cn;
        }
        __syncthreads();

        // ---- C: cell2 gates, split across all 256 threads
        if (t < 128) {
            float a0 = b2, a1 = 0.f, a2 = 0.f, a3 = 0.f;
#pragma unroll
            for (int j = 0; j < 16; ++j) {
                float4 h = ((const float4*)h1s)[j];
                a0 += wu[4*j+0] * h.x; a1 += wu[4*j+1] * h.y;
                a2 += wu[4*j+2] * h.z; a3 += wu[4*j+3] * h.w;
            }
            act2[t] = (a0 + a1) + (a2 + a3);
        } else {
            float a0 = 0.f, a1 = 0.f, a2 = 0.f, a3 = 0.f;
#pragma unroll
            for (int j = 0; j < 8; ++j) {
                float4 h = ((const float4*)h2s)[j];
                a0 += wu[4*j+0] * h.x; a1 += wu[4*j+1] * h.y;
                a2 += wu[4*j+2] * h.z; a3 += wu[4*j+3] * h.w;
            }
            act2p[t - 128] = (a0 + a1) + (a2 + a3);
        }
        __syncthreads();

        // ---- D: sum partials, activations, finish cell2, store trajectory
        if (t < 32) {
            float iv = sigf(act2[t]       + act2p[t]);
            float fv = sigf(act2[32 + t]  + act2p[32 + t]);
            float gv = tanhf(act2[64 + t] + act2p[64 + t]);
            float ov = sigf(act2[96 + t]  + act2p[96 + t]);
            float cn = fv * c2r + iv * gv;
            c2r = cn;
            float hn = ov * tanhf(cn);
            h2s[t] = hn;
            h2t[s * 32 + t] = hn;
            c2t[s * 32 + t] = cn;
        }
        // no barrier: D's writes (h2s, h2t/c2t) are untouched by next A;
        // next C reads h2s only after two intervening barriers.
    }
}

// ---------------------------------------------------------------------------
// Stage 6: forecast branch + both heads — FULLY PARALLEL over 512 steps.
// fh1 = cell1(fx_s, h1_s, c1_s); fh2 = cell2(fh1, h2_s, c2_s);
// out[s] = sig(Wfc8·h2_s + b); out[512+s] = sig(Wfc8·fh2 + b).
// One block (256 threads) per step.
// ---------------------------------------------------------------------------
__global__ __launch_bounds__(256) void forecast_kernel(const float* __restrict__ gf,
                                                       const float* __restrict__ Whh1,
                                                       const float* __restrict__ Wih2,
                                                       const float* __restrict__ Whh2,
                                                       const float* __restrict__ bih2,
                                                       const float* __restrict__ bhh2,
                                                       const float* __restrict__ h1t,
                                                       const float* __restrict__ c1t,
                                                       const float* __restrict__ h2t,
                                                       const float* __restrict__ c2t,
                                                       const float* __restrict__ Wfc8,
                                                       const float* __restrict__ bfc8,
                                                       float* __restrict__ out) {
    int s = blockIdx.x;
    int t = threadIdx.x;

    __shared__ __align__(16) float h1v[64];
    __shared__ __align__(16) float h2v[32];
    __shared__ __align__(16) float fh1[64];
    __shared__ float a1s[256];
    __shared__ float a2s[128];

    if (t < 64) h1v[t] = h1t[s * 64 + t];
    else if (t < 96) h2v[t - 64] = h2t[s * 32 + (t - 64)];
    __syncthreads();

    // forecast-cell1 gates: gf + Whh1·h1_s
    {
        const float* wr = Whh1 + t * 64;
        float a0 = 0.f, a1 = 0.f, a2 = 0.f, a3 = 0.f;
#pragma unroll
        for (int j = 0; j < 16; ++j) {
            float4 h = ((const float4*)h1v)[j];
            a0 += wr[4*j+0] * h.x; a1 += wr[4*j+1] * h.y;
            a2 += wr[4*j+2] * h.z; a3 += wr[4*j+3] * h.w;
        }
        a1s[t] = act_fun(gf[s * 256 + t] + ((a0 + a1) + (a2 + a3)), t >> 6);
    }
    __syncthreads();

    if (t < 64) {
        float iv = a1s[t], fv = a1s[64+t], gv = a1s[128+t], ov = a1s[192+t];
        float cf = fv * c1t[s * 64 + t] + iv * gv;
        fh1[t] = ov * tanhf(cf);
    }
    __syncthreads();

    // forecast-cell2 gates: Wih2·fh1 + Whh2·h2_s + b2
    if (t < 128) {
        const float* wi = Wih2 + t * 64;
        const float* wh = Whh2 + t * 32;
        float a0 = bih2[t] + bhh2[t], a1 = 0.f, a2 = 0.f, a3 = 0.f;
#pragma unroll
        for (int j = 0; j < 16; ++j) {
            float4 h = ((const float4*)fh1)[j];
            a0 += wi[4*j+0] * h.x; a1 += wi[4*j+1] * h.y;
            a2 += wi[4*j+2] * h.z; a3 += wi[4*j+3] * h.w;
        }
#pragma unroll
        for (int j = 0; j < 8; ++j) {
            float4 h = ((const float4*)h2v)[j];
            a0 += wh[4*j+0] * h.x; a1 += wh[4*j+1] * h.y;
            a2 += wh[4*j+2] * h.z; a3 += wh[4*j+3] * h.w;
        }
        a2s[t] = act_fun((a0 + a1) + (a2 + a3), (t >> 5) & 3);
    }
    __syncthreads();

    // finish forecast-cell2 + both heads (wave 0, lanes 0..31 carry values)
    if (t < 64) {
        float pv = 0.f, fv2 = 0.f;
        if (t < 32) {
            float iv = a2s[t], fv = a2s[32+t], gv = a2s[64+t], ov = a2s[96+t];
            float cf2 = fv * c2t[s * 32 + t] + iv * gv;
            float fh2 = ov * tanhf(cf2);
            float w8 = Wfc8[t];
            pv  = w8 * h2v[t];
            fv2 = w8 * fh2;
        }
#pragma unroll
        for (int off = 16; off > 0; off >>= 1) {
            pv  += __shfl_xor(pv, off);
            fv2 += __shfl_xor(fv2, off);
        }
        if (t == 0) {
            float bf8 = bfc8[0];
            out[s]       = sigf(pv + bf8);
            out[512 + s] = sigf(fv2 + bf8);
        }
    }
}

// ---------------------------------------------------------------------------
extern "C" void kernel_launch(void* const* d_in, const int* in_sizes, int n_in,
                              void* d_out, int out_size, void* d_ws, size_t ws_size,
                              hipStream_t stream) {
    const float* frames  = (const float*)d_in[0];
    const float* W_spp   = (const float*)d_in[1];
    const float* b_spp   = (const float*)d_in[2];
    const float* W_fc7   = (const float*)d_in[3];
    const float* b_fc7   = (const float*)d_in[4];
    const float* W_fcast = (const float*)d_in[5];
    const float* b_fcast = (const float*)d_in[6];
    const float* Wih1    = (const float*)d_in[7];
    const float* Whh1    = (const float*)d_in[8];
    const float* bih1    = (const float*)d_in[9];
    const float* bhh1    = (const float*)d_in[10];
    const float* Wih2    = (const float*)d_in[11];
    const float* Whh2    = (const float*)d_in[12];
    const float* bih2    = (const float*)d_in[13];
    const float* bhh2    = (const float*)d_in[14];
    const float* W_fc8   = (const float*)d_in[15];
    const float* b_fc8   = (const float*)d_in[16];
    float* out = (float*)d_out;

    float* ws     = (float*)d_ws;
    float* pooled = ws;                       // 512*90
    float* prelu  = pooled + 512 * 90;        // 512*4096
    float* emb    = prelu + 512 * 4096;       // 512*64
    float* fca    = emb + 512 * 64;           // 512*64
    float* gm     = fca + 512 * 64;           // 512*256
    float* gf     = gm + 512 * 256;           // 512*256
    float* h1t    = gf + 512 * 256;           // 512*64
    float* c1t    = h1t + 512 * 64;           // 512*64
    float* h2t    = c1t + 512 * 64;           // 512*32
    float* c2t    = h2t + 512 * 32;           // 512*32

    spp_kernel<<<1536, 192, 0, stream>>>(frames, pooled);
    fc_spp_kernel<<<dim3(4, 64), 256, 0, stream>>>(pooled, W_spp, b_spp, prelu);
    fc7cast_kernel<<<128, 512, 0, stream>>>(prelu, W_fc7, b_fc7, W_fcast, b_fcast, emb, fca);
    pregate_kernel<<<512, 256, 0, stream>>>(emb, fca, Wih1, bih1, bhh1, gm, gf);
    lstm_main_kernel<<<1, 256, 0, stream>>>(gm, Whh1, Wih2, Whh2, bih2, bhh2,
                                            h1t, c1t, h2t, c2t);
    forecast_kernel<<<512, 256, 0, stream>>>(gf, Whh1, Wih2, Whh2, bih2, bhh2,
                                             h1t, c1t, h2t, c2t, W_fc8, b_fc8, out);
}